// Round 1
// baseline (579.882 us; speedup 1.0000x reference)
//
#include <hip/hip_runtime.h>
#include <math.h>

// Problem constants
#define NPIX  36864            // 192*192
#define PI2   6.28318530717958647692f

// Workspace layout (bytes)
#define TW_OFF   0             // 192 float2 twiddles e^{+2pi i n/192}
#define PC_OFF   1536          // 6*576 floats gabor params [field][s][i][o]
#define IDX_OFF  15360         // 192*2 ints shifted intervals [o][i]{lo,hi}
#define M2_OFF   16896         // 64*64 M2 + 64 m1 floats (zeroed)
#define BN_OFF   33536         // 192 scale + 192 shift
#define T1_OFF   35072         // 12*36864 float2 stage-1 DFT
#define XS_OFF   3574016       // 12*36864 float2 shifted spectrum
#define AH_OFF   7112960       // 36864 float2 ifftshifted A_tot
#define WS_REQ   7407872

// ---------------- K0: precompute twiddles, gabor params, intervals ----------
__global__ void k_pre(const float* freq, const float* theta, const float* sigma,
                      const float* f0, const float* theta0, const float* fbs,
                      char* ws) {
    float2* tw  = (float2*)(ws + TW_OFF);
    float*  pc  = (float*)(ws + PC_OFF);
    int*    idx = (int*)(ws + IDX_OFF);
    int tid = threadIdx.x;
    for (int n = tid; n < 192; n += blockDim.x) {
        float th = PI2 * (float)n / 192.0f;
        tw[n] = make_float2(cosf(th), sinf(th));
    }
    for (int t = tid; t < 576; t += blockDim.x) {
        int s = t / 192, rem = t % 192, o = rem / 3, i = rem % 3; // layout [s][o][i]
        float fr = freq[t], th = theta[t], sg = sigma[t], f0v = f0[t], th0 = theta0[t];
        float lg  = logf(sg / f0v);
        float a1  = -1.0f / (2.0f * lg * lg);
        float lf0 = logf(f0v);
        float a2  = -1.0f / (2.0f * th0 * th0);
        float sc  = 1.0f / (PI2 * sg * sg);
        int pidx = (s*3 + i)*64 + o;
        pc[0*576 + pidx] = a1;  pc[1*576 + pidx] = lf0;
        pc[2*576 + pidx] = a2;  pc[3*576 + pidx] = th;
        pc[4*576 + pidx] = fr;  pc[5*576 + pidx] = sc;
    }
    for (int t = tid; t < 192; t += blockDim.x) {   // t = o*3+i
        int lo = (int)floorf((fbs[t*2+0] + 1.0f) * 0.5f * 192.0f) - 96;
        int hi = (int)floorf((fbs[t*2+1] + 1.0f) * 0.5f * 192.0f) - 96;
        lo = max(0, min(96, lo));
        hi = max(0, min(96, hi));
        if (hi < lo) hi = lo;
        idx[t*2+0] = lo; idx[t*2+1] = hi;
    }
}

// ---------------- K1: stage-1 forward DFT over h (x real) -------------------
__global__ __launch_bounds__(192) void k_dft1(const float* x, char* ws) {
    __shared__ float2 twsh[192];
    const float2* tw = (const float2*)(ws + TW_OFF);
    float2* t1 = (float2*)(ws + T1_OFF);
    int tid = threadIdx.x;
    twsh[tid] = tw[tid];
    __syncthreads();
    int bi = blockIdx.x;          // 0..11  (b*3+i)
    int y0 = blockIdx.y * 4;      // 48 tiles of 4 rows
    int w  = tid;
    const float* xp = x + bi * NPIX;
    float2 acc[4];
#pragma unroll
    for (int d = 0; d < 4; d++) acc[d] = make_float2(0.f, 0.f);
    for (int h = 0; h < 192; h++) {
        float xv = xp[h*192 + w];
        int m = (h * y0) % 192;
#pragma unroll
        for (int d = 0; d < 4; d++) {
            float2 e = twsh[m];                    // e^{-i th} = (c, -s)
            acc[d].x += xv * e.x;
            acc[d].y -= xv * e.y;
            m += h; if (m >= 192) m -= 192;
        }
    }
    float2* op = t1 + bi * NPIX;
#pragma unroll
    for (int d = 0; d < 4; d++) op[(y0 + d)*192 + w] = acc[d];
}

// ---------------- K2: stage-2 forward DFT over w + full fftshift write ------
__global__ __launch_bounds__(192) void k_dft2(char* ws) {
    __shared__ float2 twsh[192];
    __shared__ float2 row[192];
    const float2* tw = (const float2*)(ws + TW_OFF);
    const float2* t1 = (const float2*)(ws + T1_OFF);
    float2* Xs = (float2*)(ws + XS_OFF);
    int tid = threadIdx.x;
    int bi = blockIdx.x, y = blockIdx.y;
    twsh[tid] = tw[tid];
    row[tid]  = t1[bi*NPIX + y*192 + tid];
    __syncthreads();
    int kx = tid;
    float2 acc = make_float2(0.f, 0.f);
    int m = 0;
    for (int w = 0; w < 192; w++) {
        float2 t = row[w];
        float2 e = twsh[m];                        // multiply by (c, -s)
        acc.x += t.x*e.x + t.y*e.y;
        acc.y += t.y*e.x - t.x*e.y;
        m += kx; if (m >= 192) m -= 192;
    }
    int b = bi / 3, i = bi % 3;
    int bs = (b + 2) & 3;
    int is = (i + 1) % 3; if (is >= 3) is -= 3;
    int ys = y + 96;  if (ys >= 192) ys -= 192;
    int ks = kx + 96; if (ks >= 192) ks -= 192;
    Xs[(bs*3 + is)*NPIX + ys*192 + ks] = acc;
}

// ---------------- K3: h1 mean + second moment (for BN stats) ----------------
__global__ __launch_bounds__(256) void k_stats(const float* w1, const float* b1v, char* ws) {
    __shared__ __align__(16) float h1t[64*68];
    const float2* Xs = (const float2*)(ws + XS_OFF);
    float* M2 = (float*)(ws + M2_OFF);
    int tid = threadIdx.x;
    int j  = tid & 63;
    int sq = tid >> 6;                  // 0..3
    float wj0 = w1[j*3+0], wj1 = w1[j*3+1], wj2 = w1[j*3+2], bj = b1v[j];
    int tj = tid & 15, tk = tid >> 4;   // 16x16 accumulation grid
    float acc[4][4], macc[4];
#pragma unroll
    for (int a = 0; a < 4; a++) { macc[a] = 0.f;
#pragma unroll
        for (int b = 0; b < 4; b++) acc[a][b] = 0.f; }
    for (int tile = blockIdx.x; tile < 2304; tile += gridDim.x) {
        int base = tile * 64;
        for (int ss = 0; ss < 16; ss++) {
            int sl = sq*16 + ss;
            int sidx = base + sl;
            int b = sidx / NPIX;
            int p = sidx - b*NPIX;
            const float2* xp = Xs + b*3*NPIX + p;
            float2 v0 = xp[0], v1 = xp[NPIX], v2 = xp[2*NPIX];
            float m0 = sqrtf(v0.x*v0.x + v0.y*v0.y);
            float m1 = sqrtf(v1.x*v1.x + v1.y*v1.y);
            float m2 = sqrtf(v2.x*v2.x + v2.y*v2.y);
            float h1 = bj + wj0*m0 + wj1*m1 + wj2*m2;
            h1t[sl*68 + j] = fmaxf(h1, 0.f);
        }
        __syncthreads();
        for (int s = 0; s < 64; s++) {
            float4 rj = *(const float4*)&h1t[s*68 + tj*4];
            float4 rk = *(const float4*)&h1t[s*68 + tk*4];
            float aj[4] = {rj.x, rj.y, rj.z, rj.w};
            float ak[4] = {rk.x, rk.y, rk.z, rk.w};
#pragma unroll
            for (int a = 0; a < 4; a++) {
                macc[a] += aj[a];
#pragma unroll
                for (int b = 0; b < 4; b++) acc[a][b] += aj[a]*ak[b];
            }
        }
        __syncthreads();
    }
#pragma unroll
    for (int a = 0; a < 4; a++)
#pragma unroll
        for (int b = 0; b < 4; b++)
            atomicAdd(&M2[(tj*4 + a)*64 + (tk*4 + b)], acc[a][b]);
    if (tk == 0)
#pragma unroll
        for (int a = 0; a < 4; a++) atomicAdd(&M2[4096 + tj*4 + a], macc[a]);
}

// ---------------- K4: BN scale/shift per channel ----------------------------
__global__ __launch_bounds__(192) void k_bn(const float* w2, const float* bnw,
                                            const float* bnb, char* ws) {
    __shared__ float w2sh[192*65];
    const float* M2 = (const float*)(ws + M2_OFF);
    const float* m1 = M2 + 4096;
    float* bnsc = (float*)(ws + BN_OFF);
    float* bnsh = bnsc + 192;
    int tid = threadIdx.x;
    for (int g = tid; g < 12288; g += 192) {
        int c = g >> 6, j = g & 63;
        w2sh[c*65 + j] = w2[g];
    }
    __syncthreads();
    const float invN = 1.0f / 147456.0f;
    int c = tid;
    const float* row = &w2sh[c*65];
    float d = 0.f;
    for (int jj = 0; jj < 64; jj++) d += row[jj] * m1[jj];
    d *= invN;
    float q = 0.f;
    for (int jj = 0; jj < 64; jj++) {
        float inner = 0.f;
        const float* m2r = M2 + jj*64;
        for (int k = 0; k < 64; k++) inner += row[k] * m2r[k];
        q += row[jj] * inner;
    }
    q *= invN;
    float var = q - d*d;
    float rstd = rsqrtf(var + 1e-5f);
    float scale = bnw[c] * rstd;
    bnsc[c] = scale;
    bnsh[c] = bnb[c] - d * scale;
}

// ---------------- K5: per-pixel attention + gabor -> A_tot (ifftshifted) ----
__global__ __launch_bounds__(256) void k_attn(const float* w1, const float* b1v,
                                              const float* w2, char* ws) {
    __shared__ float w2t[64*193];       // [j][c], stride 193: conflict-free
    __shared__ float h1sh[4][4][64];    // [wave][b][j]
    const float2* Xs = (const float2*)(ws + XS_OFF);
    const float* pc = (const float*)(ws + PC_OFF);
    const float* bnsc = (const float*)(ws + BN_OFF);
    const float* bnsh = bnsc + 192;
    float2* Ah = (float2*)(ws + AH_OFF);
    int tid = threadIdx.x;
    for (int g = tid; g < 12288; g += 256) {
        int c = g >> 6, j = g & 63;
        w2t[j*193 + c] = w2[g];
    }
    int wave = tid >> 6, lane = tid & 63;
    int pix = blockIdx.x * 4 + wave;
    int h = pix / 192, w = pix - h*192;
    // load spectrum for this pixel (lane-uniform)
    float2 xsv[4][3];
    float mag[4][3];
#pragma unroll
    for (int b = 0; b < 4; b++)
#pragma unroll
        for (int i = 0; i < 3; i++) {
            float2 v = Xs[(b*3 + i)*NPIX + pix];
            xsv[b][i] = v;
            mag[b][i] = sqrtf(v.x*v.x + v.y*v.y);
        }
    // h1 (lane = j)
    {
        int j = lane;
        float wj0 = w1[j*3+0], wj1 = w1[j*3+1], wj2 = w1[j*3+2], bj = b1v[j];
#pragma unroll
        for (int b = 0; b < 4; b++) {
            float v = bj + wj0*mag[b][0] + wj1*mag[b][1] + wj2*mag[b][2];
            h1sh[wave][b][lane] = fmaxf(v, 0.f);
        }
    }
    __syncthreads();
    // h2 for c = lane + 64k
    float acc[4][3];
#pragma unroll
    for (int b = 0; b < 4; b++)
#pragma unroll
        for (int k = 0; k < 3; k++) acc[b][k] = 0.f;
    for (int jj = 0; jj < 64; jj++) {
        float hv0 = h1sh[wave][0][jj], hv1 = h1sh[wave][1][jj];
        float hv2 = h1sh[wave][2][jj], hv3 = h1sh[wave][3][jj];
#pragma unroll
        for (int k = 0; k < 3; k++) {
            float wv = w2t[jj*193 + lane + (k << 6)];
            acc[0][k] += wv*hv0; acc[1][k] += wv*hv1;
            acc[2][k] += wv*hv2; acc[3][k] += wv*hv3;
        }
    }
    // BN + softmax over all 192 channels (wave-wide)
    float attnv[4][3];
#pragma unroll
    for (int b = 0; b < 4; b++) {
        float hn[3];
#pragma unroll
        for (int k = 0; k < 3; k++) {
            int c = lane + (k << 6);
            hn[k] = acc[b][k]*bnsc[c] + bnsh[c];
        }
        float M = fmaxf(hn[0], fmaxf(hn[1], hn[2]));
#pragma unroll
        for (int off = 32; off >= 1; off >>= 1) M = fmaxf(M, __shfl_xor(M, off));
        float e0 = expf(hn[0]-M), e1 = expf(hn[1]-M), e2 = expf(hn[2]-M);
        float s = e0 + e1 + e2;
#pragma unroll
        for (int off = 32; off >= 1; off >>= 1) s += __shfl_xor(s, off);
        float inv = 1.0f / s;
        attnv[b][0] = e0*inv; attnv[b][1] = e1*inv; attnv[b][2] = e2*inv;
    }
    // log-gabor filter values g[s=k][o=lane][i]
    float yy = -1.0f + (float)h * (2.0f/191.0f);
    float xx = -1.0f + (float)w * (2.0f/191.0f);
    float r  = sqrtf(xx*xx + yy*yy + 1e-6f);
    float lr = logf(r);
    float phi = atan2f(yy, xx);
    float gl[3][3];
#pragma unroll
    for (int k = 0; k < 3; k++)
#pragma unroll
        for (int i = 0; i < 3; i++) {
            int pidx = (k*3 + i)*64 + lane;
            float a1 = pc[pidx],        lf0 = pc[576 + pidx];
            float a2 = pc[2*576 + pidx], th = pc[3*576 + pidx];
            float fr = pc[4*576 + pidx], sc = pc[5*576 + pidx];
            float dl = lr - lf0, dp = phi - th;
            gl[k][i] = expf(a1*dl*dl + a2*dp*dp) * cosf(fr*r) * sc;
        }
    // partial A = sum_{b,i} (sum_k attn*g) * Xs
    float pre = 0.f, pim = 0.f;
#pragma unroll
    for (int b = 0; b < 4; b++)
#pragma unroll
        for (int i = 0; i < 3; i++) {
            float wr = attnv[b][0]*gl[0][i] + attnv[b][1]*gl[1][i] + attnv[b][2]*gl[2][i];
            pre += wr * xsv[b][i].x;
            pim += wr * xsv[b][i].y;
        }
#pragma unroll
    for (int off = 32; off >= 1; off >>= 1) {
        pre += __shfl_xor(pre, off);
        pim += __shfl_xor(pim, off);
    }
    if (lane == 0) {
        int hs = h + 96; if (hs >= 192) hs -= 192;
        int wsx = w + 96; if (wsx >= 192) wsx -= 192;
        Ah[hs*192 + wsx] = make_float2(pre, pim);
    }
}

// ---------------- K6: interval-masked IDFT + fused 3x3 conv + mix -----------
__global__ __launch_bounds__(192) void k_final(const float* x, const float* convw,
                                               const float* mixp, float* out, char* ws) {
    __shared__ float2 twsh[192];
    __shared__ float2 Ssh[3][96];
    __shared__ float cwsh[27];
    __shared__ int iL[3], iH[3];
    const float2* tw = (const float2*)(ws + TW_OFF);
    const int* idx = (const int*)(ws + IDX_OFF);
    const float2* Ah = (const float2*)(ws + AH_OFF);
    int tid = threadIdx.x;
    int y = blockIdx.x;
    int o = blockIdx.y;
    int op = (o + 32) & 63;            // channel roll from all-axes ifftshift
    twsh[tid] = tw[tid];
    if (tid < 27) cwsh[tid] = convw[o*27 + tid];
    if (tid < 3) { iL[tid] = idx[(op*3 + tid)*2]; iH[tid] = idx[(op*3 + tid)*2 + 1]; }
    __syncthreads();
    int l0 = iL[0], u0 = iH[0], l1 = iL[1], u1 = iH[1], l2 = iL[2], u2 = iH[2];
    int n0 = u0 - l0, n1 = u1 - l1, n2 = u2 - l2;
    int p1 = n0 + n1, T = p1 + n2;
    // Phase A: column DFT over h for each interval, at this y
    for (int t = tid; t < T; t += 192) {
        int i, off, lo, hi;
        if (t < n0)      { i = 0; off = t;      lo = l0; hi = u0; }
        else if (t < p1) { i = 1; off = t - n0; lo = l1; hi = u1; }
        else             { i = 2; off = t - p1; lo = l2; hi = u2; }
        int wq = lo + off;
        float sx = 0.f, sy = 0.f;
        int m = (lo * y) % 192;
        for (int hq = lo; hq < hi; hq++) {
            float2 a = Ah[hq*192 + wq];
            float2 e = twsh[m];                // e^{+i th}
            sx += a.x*e.x - a.y*e.y;
            sy += a.x*e.y + a.y*e.x;
            m += y; if (m >= 192) m -= 192;
        }
        Ssh[i][off] = make_float2(sx, sy);
    }
    __syncthreads();
    // Phase B: row DFT over w, real part only
    int col = tid;
    float accre = 0.f;
#pragma unroll
    for (int i = 0; i < 3; i++) {
        int lo = iL[i];
        int wi = iH[i] - lo;
        int m = (lo * col) % 192;
        for (int off = 0; off < wi; off++) {
            float2 S = Ssh[i][off];
            float2 e = twsh[m];
            accre += S.x*e.x - S.y*e.y;
            m += col; if (m >= 192) m -= 192;
        }
    }
    float xfv = accre * (1.0f / 36864.0f);
    // Phase C: 3x3 conv + mixing, loop over batch
    float mixv = mixp[0];
    float onem = 1.0f - mixv;
#pragma unroll
    for (int b = 0; b < 4; b++) {
        float s = 0.f;
#pragma unroll
        for (int i = 0; i < 3; i++) {
            const float* xp = x + (b*3 + i)*NPIX;
#pragma unroll
            for (int dy = -1; dy <= 1; dy++) {
                int yq = y + dy;
                if (yq < 0 || yq >= 192) continue;
                const float* rowp = xp + yq*192;
#pragma unroll
                for (int dx = -1; dx <= 1; dx++) {
                    int xq = col + dx;
                    if (xq < 0 || xq >= 192) continue;
                    s += rowp[xq] * cwsh[i*9 + (dy+1)*3 + (dx+1)];
                }
            }
        }
        out[((b*64 + o)*192 + y)*192 + col] = mixv*xfv + onem*s;
    }
}

extern "C" void kernel_launch(void* const* d_in, const int* in_sizes, int n_in,
                              void* d_out, int out_size, void* d_ws, size_t ws_size,
                              hipStream_t stream) {
    const float* x      = (const float*)d_in[0];
    const float* freq   = (const float*)d_in[1];
    const float* theta  = (const float*)d_in[2];
    const float* sigma  = (const float*)d_in[3];
    const float* f0     = (const float*)d_in[4];
    const float* theta0 = (const float*)d_in[5];
    const float* aw1    = (const float*)d_in[6];
    const float* ab1    = (const float*)d_in[7];
    const float* aw2    = (const float*)d_in[8];
    // d_in[9] = attn_b2: cancelled exactly by BN mean-subtraction, unused
    const float* bnw    = (const float*)d_in[10];
    const float* bnb    = (const float*)d_in[11];
    const float* mixp   = (const float*)d_in[12];
    const float* convw  = (const float*)d_in[13];
    const float* fbs    = (const float*)d_in[14];
    float* out = (float*)d_out;
    char* ws = (char*)d_ws;
    if (ws_size < (size_t)WS_REQ) return;  // fail loudly rather than corrupt

    hipMemsetAsync(ws + M2_OFF, 0, 16640, stream);
    k_pre  <<<1, 256, 0, stream>>>(freq, theta, sigma, f0, theta0, fbs, ws);
    k_dft1 <<<dim3(12, 48),  192, 0, stream>>>(x, ws);
    k_dft2 <<<dim3(12, 192), 192, 0, stream>>>(ws);
    k_stats<<<288, 256, 0, stream>>>(aw1, ab1, ws);
    k_bn   <<<1, 192, 0, stream>>>(aw2, bnw, bnb, ws);
    k_attn <<<9216, 256, 0, stream>>>(aw1, ab1, aw2, ws);
    k_final<<<dim3(192, 64), 192, 0, stream>>>(x, convw, mixp, out, ws);
}